// Round 2
// baseline (506.656 us; speedup 1.0000x reference)
//
#include <hip/hip_runtime.h>

// Problem constants
#define DD 128    // nodes / input dim
#define HH 512    // hidden
#define NN 2048   // batch rows
#define NT 64     // rows per block tile
#define H1_LD 520 // 512 + 8 bf16 pad
#define PLD 516   // pack LDS leading dim: row stride 1032B = 8B-aligned, <=2-way banks

typedef __bf16 bf16x8 __attribute__((ext_vector_type(8)));
typedef __bf16 bf16x4 __attribute__((ext_vector_type(4)));
typedef float  floatx4 __attribute__((ext_vector_type(4)));

// ---------------------------------------------------------------------------
// x (fp32 row-major) -> xb (bf16 row-major). 2048x128, 16B/thread.
// ---------------------------------------------------------------------------
__global__ void cvt_x(const float* __restrict__ x, __bf16* __restrict__ xb) {
    int t = blockIdx.x * blockDim.x + threadIdx.x;
    float4 v = *(const float4*)(x + (size_t)t * 4);
    bf16x4 o;
    o[0] = (__bf16)v.x; o[1] = (__bf16)v.y; o[2] = (__bf16)v.z; o[3] = (__bf16)v.w;
    *(bf16x4*)(xb + (size_t)t * 4) = o;
}

// ---------------------------------------------------------------------------
// Pack W[d][K][H] fp32 -> bf16 MFMA-B-frag order via LDS transpose.
//   Wp[((((d*32+ct)*nks+ks)*4+q)*16+c)*8+j] = bf16(W[d][ks*32+q*8+j][ct*16+c])
// One block per (d, ks): reads a 32x512 tile coalesced (float4), transposes
// through LDS, writes 16B chunks coalesced (1KB/wave).
// ---------------------------------------------------------------------------
__global__ void pack_w(const float* __restrict__ W, __bf16* __restrict__ Wp, int nks) {
    __shared__ __bf16 Ls[32 * PLD];
    const int d  = blockIdx.x / nks;
    const int ks = blockIdx.x % nks;
    const int tid = threadIdx.x;
    const float* src = W + ((size_t)(d * nks + ks) * 32) * HH;  // rows ks*32.. of W[d]

#pragma unroll
    for (int it = 0; it < 16; ++it) {
        int e = (it * 256 + tid) * 4;     // 0..16383, row=e>>9, col=e&511
        float4 v = *(const float4*)(src + e);
        bf16x4 o;
        o[0] = (__bf16)v.x; o[1] = (__bf16)v.y; o[2] = (__bf16)v.z; o[3] = (__bf16)v.w;
        *(bf16x4*)(Ls + (e >> 9) * PLD + (e & 511)) = o;
    }
    __syncthreads();

#pragma unroll
    for (int it = 0; it < 8; ++it) {
        int ch = it * 256 + tid;          // 0..2047: c=ch&15, q=(ch>>4)&3, ct=ch>>6
        int c  = ch & 15;
        int q  = (ch >> 4) & 3;
        int ct = ch >> 6;
        bf16x8 v;
#pragma unroll
        for (int j = 0; j < 8; ++j)
            v[j] = Ls[(q * 8 + j) * PLD + ct * 16 + c];
        *(bf16x8*)(Wp + ((size_t)(d * 32 + ct) * nks + ks) * 512 + (ch & 63) * 8) = v;
    }
}

// ---------------------------------------------------------------------------
// Fused per-(d, row-tile) MLP:
//   phase 1: h1 = leaky(Xmask @ W0[d])  (A-frags straight from global xb,
//                                        diagonal mask applied in-register)
//   phase 2: h2 = leaky(h1 @ W1[d])     (h1 via LDS round-trip, bf16)
//   phase 3: out = h2 @ W2[d]           (fp32, straight from accumulators)
// MFMA 16x16x32 bf16. A[m=lane&15][k=quad*8+j]; B[k=quad*8+j][n=lane&15];
// C/D: col=lane&15, row=quad*4+reg.
// ---------------------------------------------------------------------------
__launch_bounds__(512, 4)
__global__ void grandag_main(const __bf16* __restrict__ xb,
                             const __bf16* __restrict__ W0p,
                             const __bf16* __restrict__ W1p,
                             const float* __restrict__ W2,
                             float* __restrict__ out) {
    __shared__ __bf16 h1s[NT * H1_LD];   // 66560 B
    __shared__ float  outp[NT];          // +256 B -> 2 blocks/CU

    const int b  = blockIdx.x;
    // XCD swizzle: d % 8 == blockIdx % 8 -> all 32 tiles of a d on one XCD
    const int d  = ((b >> 8) << 3) | (b & 7);
    const int t  = (b >> 3) & 31;
    const int n0 = t * NT;

    const int tid = threadIdx.x;
    const int w   = tid >> 6;   // wave 0..7: owns h-cols [w*64, w*64+64)
    const int l   = tid & 63;
    const int lc  = l & 15;     // MFMA n/m index
    const int lq  = l >> 4;     // MFMA k-quad

    const int ksz = d >> 5;          // k-slice containing column d
    const int lqz = (d >> 3) & 3;    // quad containing column d
    const int jz  = d & 7;           // element containing column d

    if (tid < NT) outp[tid] = 0.f;

    // ---- phase 1: acc[rt][ct] = Xmask(16rt..) @ W0[d](:, w*64+16ct..)
    {
        floatx4 acc[4][4] = {};
        bf16x8 af[2][4], bfm[2][4];
        auto loadA = [&](bf16x8* a, int ks) {
#pragma unroll
            for (int rt = 0; rt < 4; rt++)
                a[rt] = *(const bf16x8*)(xb + (size_t)(n0 + 16 * rt + lc) * DD + ks * 32 + lq * 8);
            if (ks == ksz && lq == lqz) {   // zero column d (the mask)
#pragma unroll
                for (int rt = 0; rt < 4; rt++)
#pragma unroll
                    for (int j = 0; j < 8; j++)
                        if (j == jz) a[rt][j] = (__bf16)0.f;
            }
        };
        auto loadB = [&](bf16x8* bb, int ks) {
#pragma unroll
            for (int ct = 0; ct < 4; ct++)
                bb[ct] = *(const bf16x8*)(W0p +
                    ((((size_t)d * 32 + (w * 4 + ct)) * 4 + ks) * 64 + lq * 16 + lc) * 8);
        };
        loadA(af[0], 0); loadB(bfm[0], 0);
#pragma unroll
        for (int ks = 0; ks < 4; ks++) {
            if (ks < 3) { loadA(af[(ks + 1) & 1], ks + 1); loadB(bfm[(ks + 1) & 1], ks + 1); }
#pragma unroll
            for (int rt = 0; rt < 4; rt++)
#pragma unroll
                for (int ct = 0; ct < 4; ct++)
                    acc[rt][ct] = __builtin_amdgcn_mfma_f32_16x16x32_bf16(
                        af[ks & 1][rt], bfm[ks & 1][ct], acc[rt][ct], 0, 0, 0);
        }
        // leaky-relu + store h1 tile to LDS (bf16, row-major padded)
#pragma unroll
        for (int rt = 0; rt < 4; rt++)
#pragma unroll
            for (int ct = 0; ct < 4; ct++)
#pragma unroll
                for (int g = 0; g < 4; g++) {
                    float v = acc[rt][ct][g];
                    v = v > 0.f ? v : 0.01f * v;
                    h1s[(16 * rt + lq * 4 + g) * H1_LD + w * 64 + 16 * ct + lc] = (__bf16)v;
                }
    }
    __syncthreads();

    // ---- phase 2: acc2[rt][ct] = h1(16rt..) @ W1[d](:, w*64+16ct..)
    floatx4 acc2[4][4] = {};
    {
        bf16x8 af[2][4], bfm[2][4];
        auto loadA = [&](bf16x8* a, int ks) {
#pragma unroll
            for (int rt = 0; rt < 4; rt++)
                a[rt] = *(const bf16x8*)(h1s + (16 * rt + lc) * H1_LD + ks * 32 + lq * 8);
        };
        auto loadB = [&](bf16x8* bb, int ks) {
#pragma unroll
            for (int ct = 0; ct < 4; ct++)
                bb[ct] = *(const bf16x8*)(W1p +
                    ((((size_t)d * 32 + (w * 4 + ct)) * 16 + ks) * 64 + lq * 16 + lc) * 8);
        };
        loadA(af[0], 0); loadB(bfm[0], 0);
#pragma unroll
        for (int ks = 0; ks < 16; ks++) {
            if (ks < 15) { loadA(af[(ks + 1) & 1], ks + 1); loadB(bfm[(ks + 1) & 1], ks + 1); }
#pragma unroll
            for (int rt = 0; rt < 4; rt++)
#pragma unroll
                for (int ct = 0; ct < 4; ct++)
                    acc2[rt][ct] = __builtin_amdgcn_mfma_f32_16x16x32_bf16(
                        af[ks & 1][rt], bfm[ks & 1][ct], acc2[rt][ct], 0, 0, 0);
        }
    }

    // ---- phase 3: leaky(h2) @ W2[d], fp32 straight from accumulators
    float w2v[4];
#pragma unroll
    for (int ct = 0; ct < 4; ct++)
        w2v[ct] = W2[(size_t)d * HH + w * 64 + 16 * ct + lc];
#pragma unroll
    for (int rt = 0; rt < 4; rt++)
#pragma unroll
        for (int g = 0; g < 4; g++) {
            float s = 0.f;
#pragma unroll
            for (int ct = 0; ct < 4; ct++) {
                float v = acc2[rt][ct][g];
                v = v > 0.f ? v : 0.01f * v;
                s += v * w2v[ct];
            }
            // reduce the 16 column-lanes inside this quad
            s += __shfl_xor(s, 1, 64);
            s += __shfl_xor(s, 2, 64);
            s += __shfl_xor(s, 4, 64);
            s += __shfl_xor(s, 8, 64);
            if (lc == 0) atomicAdd(&outp[16 * rt + lq * 4 + g], s);
        }
    __syncthreads();
    if (tid < NT) out[(size_t)(n0 + tid) * DD + d] = outp[tid];
}

// ---------------------------------------------------------------------------
extern "C" void kernel_launch(void* const* d_in, const int* in_sizes, int n_in,
                              void* d_out, int out_size, void* d_ws, size_t ws_size,
                              hipStream_t stream) {
    const float* x  = (const float*)d_in[0];
    const float* W0 = (const float*)d_in[1];
    const float* W1 = (const float*)d_in[2];
    const float* W2 = (const float*)d_in[3];
    float* out = (float*)d_out;

    __bf16* W0p = (__bf16*)d_ws;                                          // 16.8 MB
    __bf16* W1p = (__bf16*)((char*)d_ws + (size_t)DD * DD * HH * 2);      // 67.1 MB
    __bf16* xb  = (__bf16*)((char*)d_ws + (size_t)DD * DD * HH * 2
                                        + (size_t)DD * HH * HH * 2);      // 0.5 MB

    cvt_x<<<dim3(NN * DD / (256 * 4)), 256, 0, stream>>>(x, xb);
    pack_w<<<dim3(DD * (DD / 32)), 256, 0, stream>>>(W0, W0p, DD / 32);   // 512 blocks
    pack_w<<<dim3(DD * (HH / 32)), 256, 0, stream>>>(W1, W1p, HH / 32);   // 2048 blocks

    grandag_main<<<dim3(DD * (NN / NT)), 512, 0, stream>>>(xb, W0p, W1p, W2, out);
}

// Round 3
// 432.442 us; speedup vs baseline: 1.1716x; 1.1716x over previous
//
#include <hip/hip_runtime.h>

// Problem constants
#define DD 128    // nodes / input dim
#define HH 512    // hidden
#define NN 2048   // batch rows
#define NT 64     // rows per block tile
#define H1_LD 520 // 512 + 8 bf16 pad
#define PLD 516   // pack LDS leading dim: row stride 1032B = 8B-aligned, <=2-way banks

typedef __bf16 bf16x8 __attribute__((ext_vector_type(8)));
typedef __bf16 bf16x4 __attribute__((ext_vector_type(4)));
typedef float  floatx4 __attribute__((ext_vector_type(4)));

// ---------------------------------------------------------------------------
// x (fp32 row-major) -> xb (bf16 row-major). 2048x128, 16B/thread.
// ---------------------------------------------------------------------------
__global__ void cvt_x(const float* __restrict__ x, __bf16* __restrict__ xb) {
    int t = blockIdx.x * blockDim.x + threadIdx.x;
    float4 v = *(const float4*)(x + (size_t)t * 4);
    bf16x4 o;
    o[0] = (__bf16)v.x; o[1] = (__bf16)v.y; o[2] = (__bf16)v.z; o[3] = (__bf16)v.w;
    *(bf16x4*)(xb + (size_t)t * 4) = o;
}

// ---------------------------------------------------------------------------
// Pack W[d][K][H] fp32 -> bf16 MFMA-B-frag order via LDS transpose.
//   Wp[((((d*32+ct)*nks+ks)*4+q)*16+c)*8+j] = bf16(W[d][ks*32+q*8+j][ct*16+c])
// One block per (d, ks): reads a 32x512 tile coalesced (float4), transposes
// through LDS, writes 16B chunks coalesced (1KB/wave).
// ---------------------------------------------------------------------------
__global__ void pack_w(const float* __restrict__ W, __bf16* __restrict__ Wp, int nks) {
    __shared__ __bf16 Ls[32 * PLD];
    const int d  = blockIdx.x / nks;
    const int ks = blockIdx.x % nks;
    const int tid = threadIdx.x;
    const float* src = W + ((size_t)(d * nks + ks) * 32) * HH;  // rows ks*32.. of W[d]

#pragma unroll
    for (int it = 0; it < 16; ++it) {
        int e = (it * 256 + tid) * 4;     // 0..16383, row=e>>9, col=e&511
        float4 v = *(const float4*)(src + e);
        bf16x4 o;
        o[0] = (__bf16)v.x; o[1] = (__bf16)v.y; o[2] = (__bf16)v.z; o[3] = (__bf16)v.w;
        *(bf16x4*)(Ls + (e >> 9) * PLD + (e & 511)) = o;
    }
    __syncthreads();

#pragma unroll
    for (int it = 0; it < 8; ++it) {
        int ch = it * 256 + tid;          // 0..2047: c=ch&15, q=(ch>>4)&3, ct=ch>>6
        int c  = ch & 15;
        int q  = (ch >> 4) & 3;
        int ct = ch >> 6;
        bf16x8 v;
#pragma unroll
        for (int j = 0; j < 8; ++j)
            v[j] = Ls[(q * 8 + j) * PLD + ct * 16 + c];
        *(bf16x8*)(Wp + ((size_t)(d * 32 + ct) * nks + ks) * 512 + (ch & 63) * 8) = v;
    }
}

// ---------------------------------------------------------------------------
// Fused per-(d, row-tile) MLP:
//   phase 1: h1 = leaky(Xmask @ W0[d])  (A-frags straight from global xb,
//                                        diagonal mask applied in-register)
//   phase 2: h2 = leaky(h1 @ W1[d])     (h1 via LDS round-trip, bf16)
//   phase 3: out = h2 @ W2[d]           (fp32, straight from accumulators)
// MFMA 16x16x32 bf16. A[m=lane&15][k=quad*8+j]; B[k=quad*8+j][n=lane&15];
// C/D: col=lane&15, row=quad*4+reg.
// Register budget note: 64 acc + 32 single-buffered frags + ~16 addr fits the
// 128-VGPR cap of (512,4); round-2's explicit double-buffer (192 live) spilled
// 400 MB to scratch. Let the compiler pipeline within the cap.
// ---------------------------------------------------------------------------
__launch_bounds__(512, 4)
__global__ void grandag_main(const __bf16* __restrict__ xb,
                             const __bf16* __restrict__ W0p,
                             const __bf16* __restrict__ W1p,
                             const float* __restrict__ W2,
                             float* __restrict__ out) {
    __shared__ __bf16 h1s[NT * H1_LD];   // 66560 B
    __shared__ float  outp[NT];          // +256 B -> 2 blocks/CU

    const int b  = blockIdx.x;
    // XCD swizzle: d % 8 == blockIdx % 8 -> all 32 tiles of a d on one XCD
    const int d  = ((b >> 8) << 3) | (b & 7);
    const int t  = (b >> 3) & 31;
    const int n0 = t * NT;

    const int tid = threadIdx.x;
    const int w   = tid >> 6;   // wave 0..7: owns h-cols [w*64, w*64+64)
    const int l   = tid & 63;
    const int lc  = l & 15;     // MFMA n/m index
    const int lq  = l >> 4;     // MFMA k-quad

    const int ksz = d >> 5;          // k-slice containing column d
    const int lqz = (d >> 3) & 3;    // quad containing column d
    const int jz  = d & 7;           // element containing column d

    if (tid < NT) outp[tid] = 0.f;

    // ---- phase 1: acc[rt][ct] = Xmask(16rt..) @ W0[d](:, w*64+16ct..)
    {
        floatx4 acc[4][4] = {};
#pragma unroll
        for (int ks = 0; ks < 4; ks++) {
            bf16x8 af[4], bfm[4];
#pragma unroll
            for (int rt = 0; rt < 4; rt++)
                af[rt] = *(const bf16x8*)(xb + (size_t)(n0 + 16 * rt + lc) * DD + ks * 32 + lq * 8);
            if (ks == ksz && lq == lqz) {   // zero column d (the mask)
#pragma unroll
                for (int rt = 0; rt < 4; rt++)
#pragma unroll
                    for (int j = 0; j < 8; j++)
                        if (j == jz) af[rt][j] = (__bf16)0.f;
            }
#pragma unroll
            for (int ct = 0; ct < 4; ct++)
                bfm[ct] = *(const bf16x8*)(W0p +
                    ((((size_t)d * 32 + (w * 4 + ct)) * 4 + ks) * 64 + lq * 16 + lc) * 8);
#pragma unroll
            for (int rt = 0; rt < 4; rt++)
#pragma unroll
                for (int ct = 0; ct < 4; ct++)
                    acc[rt][ct] = __builtin_amdgcn_mfma_f32_16x16x32_bf16(
                        af[rt], bfm[ct], acc[rt][ct], 0, 0, 0);
        }
        // leaky-relu + store h1 tile to LDS (bf16, row-major padded)
#pragma unroll
        for (int rt = 0; rt < 4; rt++)
#pragma unroll
            for (int ct = 0; ct < 4; ct++)
#pragma unroll
                for (int g = 0; g < 4; g++) {
                    float v = acc[rt][ct][g];
                    v = v > 0.f ? v : 0.01f * v;
                    h1s[(16 * rt + lq * 4 + g) * H1_LD + w * 64 + 16 * ct + lc] = (__bf16)v;
                }
    }
    __syncthreads();

    // ---- phase 2: acc2[rt][ct] = h1(16rt..) @ W1[d](:, w*64+16ct..)
    floatx4 acc2[4][4] = {};
#pragma unroll
    for (int ks = 0; ks < 16; ks++) {
        bf16x8 af[4], bfm[4];
#pragma unroll
        for (int rt = 0; rt < 4; rt++)
            af[rt] = *(const bf16x8*)(h1s + (16 * rt + lc) * H1_LD + ks * 32 + lq * 8);
#pragma unroll
        for (int ct = 0; ct < 4; ct++)
            bfm[ct] = *(const bf16x8*)(W1p +
                ((((size_t)d * 32 + (w * 4 + ct)) * 16 + ks) * 64 + lq * 16 + lc) * 8);
#pragma unroll
        for (int rt = 0; rt < 4; rt++)
#pragma unroll
            for (int ct = 0; ct < 4; ct++)
                acc2[rt][ct] = __builtin_amdgcn_mfma_f32_16x16x32_bf16(
                    af[rt], bfm[ct], acc2[rt][ct], 0, 0, 0);
    }

    // ---- phase 3: leaky(h2) @ W2[d], fp32 straight from accumulators
    float w2v[4];
#pragma unroll
    for (int ct = 0; ct < 4; ct++)
        w2v[ct] = W2[(size_t)d * HH + w * 64 + 16 * ct + lc];
#pragma unroll
    for (int rt = 0; rt < 4; rt++)
#pragma unroll
        for (int g = 0; g < 4; g++) {
            float s = 0.f;
#pragma unroll
            for (int ct = 0; ct < 4; ct++) {
                float v = acc2[rt][ct][g];
                v = v > 0.f ? v : 0.01f * v;
                s += v * w2v[ct];
            }
            // reduce the 16 column-lanes inside this quad
            s += __shfl_xor(s, 1, 64);
            s += __shfl_xor(s, 2, 64);
            s += __shfl_xor(s, 4, 64);
            s += __shfl_xor(s, 8, 64);
            if (lc == 0) atomicAdd(&outp[16 * rt + lq * 4 + g], s);
        }
    __syncthreads();
    if (tid < NT) out[(size_t)(n0 + tid) * DD + d] = outp[tid];
}

// ---------------------------------------------------------------------------
extern "C" void kernel_launch(void* const* d_in, const int* in_sizes, int n_in,
                              void* d_out, int out_size, void* d_ws, size_t ws_size,
                              hipStream_t stream) {
    const float* x  = (const float*)d_in[0];
    const float* W0 = (const float*)d_in[1];
    const float* W1 = (const float*)d_in[2];
    const float* W2 = (const float*)d_in[3];
    float* out = (float*)d_out;

    __bf16* W0p = (__bf16*)d_ws;                                          // 16.8 MB
    __bf16* W1p = (__bf16*)((char*)d_ws + (size_t)DD * DD * HH * 2);      // 67.1 MB
    __bf16* xb  = (__bf16*)((char*)d_ws + (size_t)DD * DD * HH * 2
                                        + (size_t)DD * HH * HH * 2);      // 0.5 MB

    cvt_x<<<dim3(NN * DD / (256 * 4)), 256, 0, stream>>>(x, xb);
    pack_w<<<dim3(DD * (DD / 32)), 256, 0, stream>>>(W0, W0p, DD / 32);   // 512 blocks
    pack_w<<<dim3(DD * (HH / 32)), 256, 0, stream>>>(W1, W1p, HH / 32);   // 2048 blocks

    grandag_main<<<dim3(DD * (NN / NT)), 512, 0, stream>>>(xb, W0p, W1p, W2, out);
}